// Round 2
// baseline (768.596 us; speedup 1.0000x reference)
//
#include <hip/hip_runtime.h>
#include <cstddef>

#define NN 1024
#define DD 6
#define TT 60
#define HH 64
#define RR 64
#define NEGV  (-10000.0f)
#define SLOPEV (0.01f)
#define SS 4            // samples per GRU block

__device__ __forceinline__ float sig_(float x)  { return 1.0f / (1.0f + __expf(-x)); }
__device__ __forceinline__ float tanh_(float x) { return 1.0f - 2.0f / (__expf(2.0f * x) + 1.0f); }

// ---------------------------------------------------------------------------
// k_rel: stream the 268 MB relation tensor. 16-lane group per (i,j) pair:
// float4 per lane, butterfly reduce, lanes {0,16,32,48} store 4 contiguous
// results. 1024 blocks x 256 threads, fully coalesced 1 KiB/wave/iter.
// ---------------------------------------------------------------------------
__global__ __launch_bounds__(256)
void k_rel(const float* __restrict__ rel, const float* __restrict__ W,
           float* __restrict__ sr, float* __restrict__ ssum)
{
    const int lane = threadIdx.x & 63;
    const int gw   = (blockIdx.x * 256 + threadIdx.x) >> 6;   // 0..4095
    const int sub  = lane >> 4;
    const int l16  = lane & 15;
    const float4 wv2 = *(const float4*)(W + 2 * HH + l16 * 4);
    for (int p0 = gw * 4; p0 < NN * NN; p0 += 4096 * 4) {
        const int p = p0 + sub;
        const float4 v = *(const float4*)(rel + (size_t)p * RR + l16 * 4);
        float dt = v.x * wv2.x + v.y * wv2.y + v.z * wv2.z + v.w * wv2.w;
        float sm = v.x + v.y + v.z + v.w;
        #pragma unroll
        for (int m = 8; m >= 1; m >>= 1) {
            dt += __shfl_xor(dt, m);
            sm += __shfl_xor(sm, m);
        }
        if (l16 == 0) { sr[p] = dt; ssum[p] = sm; }
    }
}

// ---------------------------------------------------------------------------
// k_gru: 256 blocks x 192 threads, SS=4 samples/block. Phase-split so the
// live register set never exceeds ~180 (no spill):
//   phase0: layer-0 recurrence (w0: 64 + wi0: 6 regs), h0(t) kept in LDS
//   phase1: layer-1 recurrence (wi1 + w1: 128 regs) consuming h0seq
// Epilogue: per-sample scalars sa, sb, hdot (h.fc1), hb (h.fc2).
// ---------------------------------------------------------------------------
__global__ __launch_bounds__(192, 1)
void k_gru(const float* __restrict__ x,
           const float* __restrict__ W, const float* __restrict__ fc_w,
           const float* __restrict__ Wih0, const float* __restrict__ Whh0,
           const float* __restrict__ bih0, const float* __restrict__ bhh0,
           const float* __restrict__ Wih1, const float* __restrict__ Whh1,
           const float* __restrict__ bih1, const float* __restrict__ bhh1,
           float* __restrict__ sa, float* __restrict__ sb,
           float* __restrict__ hdot, float* __restrict__ hb)
{
    const int nb = blockIdx.x * SS;
    const int j  = threadIdx.x;                 // gate row 0..191

    __shared__ __align__(16) float xls[SS * DD * TT];     //  5.76 KB
    __shared__ __align__(16) float h0seq[SS * TT * HH];   // 61.44 KB
    __shared__ __align__(16) float h0c[SS * HH];
    __shared__ __align__(16) float h1c[SS * HH];
    __shared__ __align__(16) float Ag[SS * 3 * HH];
    __shared__ __align__(16) float Bg[SS * HH];

    for (int idx = j; idx < SS * DD * TT; idx += 192)
        xls[idx] = x[nb * DD * TT + idx];
    if (j < HH) {
        #pragma unroll
        for (int s = 0; s < SS; ++s) { h0c[s * HH + j] = 0.0f; h1c[s * HH + j] = 0.0f; }
    }

    // ---------------- phase 0: layer-0 recurrence ----------------
    float wr[HH];                                // Whh0 row j
    #pragma unroll
    for (int kk = 0; kk < HH / 4; ++kk) {
        const float4 v = *(const float4*)(Whh0 + j * HH + kk * 4);
        wr[4*kk] = v.x; wr[4*kk+1] = v.y; wr[4*kk+2] = v.z; wr[4*kk+3] = v.w;
    }
    float wi0[DD];
    #pragma unroll
    for (int d = 0; d < DD; ++d) wi0[d] = Wih0[j * DD + d];
    const float bi0 = bih0[j], bh0 = bhh0[j];
    __syncthreads();

    for (int t = 0; t < TT; ++t) {
        float hg[SS];
        #pragma unroll
        for (int s = 0; s < SS; ++s) hg[s] = bh0;
        #pragma unroll
        for (int kk = 0; kk < HH / 4; ++kk) {
            #pragma unroll
            for (int s = 0; s < SS; ++s) {
                const float4 hv = *((const float4*)(h0c + s * HH) + kk);
                hg[s] += wr[4*kk]*hv.x + wr[4*kk+1]*hv.y + wr[4*kk+2]*hv.z + wr[4*kk+3]*hv.w;
            }
        }
        #pragma unroll
        for (int s = 0; s < SS; ++s) {
            float xg = bi0;
            #pragma unroll
            for (int d = 0; d < DD; ++d) xg += wi0[d] * xls[s * DD * TT + d * TT + t];
            Ag[s * 192 + j] = xg + hg[s];
            if (j >= 2 * HH) Bg[s * HH + (j - 2 * HH)] = hg[s];
        }
        __syncthreads();
        for (int u = j; u < SS * HH; u += 192) {
            const int s = u >> 6, jj = u & 63;
            const float r  = sig_(Ag[s * 192 + jj]);
            const float z  = sig_(Ag[s * 192 + HH + jj]);
            const float hn = Bg[s * HH + jj];
            const float nv = tanh_(Ag[s * 192 + 2 * HH + jj] - hn + r * hn);
            const float hnew = (1.0f - z) * nv + z * h0c[s * HH + jj];
            h0c[s * HH + jj] = hnew;
            h0seq[(s * TT + t) * HH + jj] = hnew;
        }
        __syncthreads();
    }

    // ---------------- phase 1: layer-1 recurrence ----------------
    float wi1[HH], w1[HH];
    #pragma unroll
    for (int kk = 0; kk < HH / 4; ++kk) {
        const float4 a = *(const float4*)(Wih1 + j * HH + kk * 4);
        wi1[4*kk] = a.x; wi1[4*kk+1] = a.y; wi1[4*kk+2] = a.z; wi1[4*kk+3] = a.w;
        const float4 c = *(const float4*)(Whh1 + j * HH + kk * 4);
        w1[4*kk] = c.x; w1[4*kk+1] = c.y; w1[4*kk+2] = c.z; w1[4*kk+3] = c.w;
    }
    const float bi1 = bih1[j], bh1 = bhh1[j];
    __syncthreads();

    for (int t = 0; t < TT; ++t) {
        float xg1[SS], hg1[SS];
        #pragma unroll
        for (int s = 0; s < SS; ++s) { xg1[s] = bi1; hg1[s] = bh1; }
        #pragma unroll
        for (int kk = 0; kk < HH / 4; ++kk) {
            #pragma unroll
            for (int s = 0; s < SS; ++s) {
                const float4 a = *((const float4*)(h0seq + (s * TT + t) * HH) + kk);
                const float4 c = *((const float4*)(h1c + s * HH) + kk);
                xg1[s] += wi1[4*kk]*a.x + wi1[4*kk+1]*a.y + wi1[4*kk+2]*a.z + wi1[4*kk+3]*a.w;
                hg1[s] += w1[4*kk]*c.x  + w1[4*kk+1]*c.y  + w1[4*kk+2]*c.z  + w1[4*kk+3]*c.w;
            }
        }
        #pragma unroll
        for (int s = 0; s < SS; ++s) {
            Ag[s * 192 + j] = xg1[s] + hg1[s];
            if (j >= 2 * HH) Bg[s * HH + (j - 2 * HH)] = hg1[s];
        }
        __syncthreads();
        for (int u = j; u < SS * HH; u += 192) {
            const int s = u >> 6, jj = u & 63;
            const float r  = sig_(Ag[s * 192 + jj]);
            const float z  = sig_(Ag[s * 192 + HH + jj]);
            const float hn = Bg[s * HH + jj];
            const float nv = tanh_(Ag[s * 192 + 2 * HH + jj] - hn + r * hn);
            h1c[s * HH + jj] = (1.0f - z) * nv + z * h1c[s * HH + jj];
        }
        __syncthreads();
    }

    // ---------------- epilogue: per-sample scalars ----------------
    if (j < HH) {
        #pragma unroll
        for (int s = 0; s < SS; ++s) {
            const float hv = h1c[s * HH + j];
            float pa = hv * W[j];
            float pb = hv * W[HH + j];
            float pc = hv * fc_w[j];
            float pd = hv * fc_w[HH + j];
            #pragma unroll
            for (int off = 32; off >= 1; off >>= 1) {
                pa += __shfl_down(pa, off);
                pb += __shfl_down(pb, off);
                pc += __shfl_down(pc, off);
                pd += __shfl_down(pd, off);
            }
            if (j == 0) {
                sa[nb + s] = pa; sb[nb + s] = pb;
                hdot[nb + s] = pc; hb[nb + s] = pd;
            }
        }
    }
}

// ---------------------------------------------------------------------------
// k2: per row i — masked leaky scores, exact masked-softmax semantics, and
// out_i = hdot_i + (sum_j e_j * m_j * hb_j) / denom + fc_b. No h gather.
// ---------------------------------------------------------------------------
__global__ __launch_bounds__(256)
void k2(const float* __restrict__ sa, const float* __restrict__ sb,
        const float* __restrict__ hdot, const float* __restrict__ hb,
        const float* __restrict__ sr, const float* __restrict__ ssum,
        const float* __restrict__ bscal, const float* __restrict__ fc_b,
        float* __restrict__ out)
{
    __shared__ float red[12];
    const int i   = blockIdx.x;
    const int tid = threadIdx.x;
    const int j4  = tid * 4;
    const float sai = sa[i] + bscal[0];

    const float4 srv = *(const float4*)(sr   + (size_t)i * NN + j4);
    const float4 ssv = *(const float4*)(ssum + (size_t)i * NN + j4);
    const float4 sbv = *(const float4*)(sb + j4);

    float tv[4], mk[4];
    float mloc = -3.4e38f;
    {
        const float srq[4] = {srv.x, srv.y, srv.z, srv.w};
        const float ssq[4] = {ssv.x, ssv.y, ssv.z, ssv.w};
        const float sbq[4] = {sbv.x, sbv.y, sbv.z, sbv.w};
        #pragma unroll
        for (int q = 0; q < 4; ++q) {
            float w = sai + sbq[q] + srq[q];
            w = (w >= 0.0f) ? w : SLOPEV * w;
            const float m = (ssq[q] != 0.0f) ? 1.0f : 0.0f;
            float t = m * w;
            t = (t == 0.0f) ? NEGV : t;
            tv[q] = t; mk[q] = m;
            mloc = fmaxf(mloc, t);
        }
    }
    #pragma unroll
    for (int off = 32; off >= 1; off >>= 1) mloc = fmaxf(mloc, __shfl_xor(mloc, off));
    if ((tid & 63) == 0) red[tid >> 6] = mloc;
    __syncthreads();
    const float mx = fmaxf(fmaxf(red[0], red[1]), fmaxf(red[2], red[3]));

    const float4 hbv = *(const float4*)(hb + j4);
    const float hbq[4] = {hbv.x, hbv.y, hbv.z, hbv.w};
    float sloc = 0.0f, vloc = 0.0f;
    #pragma unroll
    for (int q = 0; q < 4; ++q) {
        const float e = __expf(tv[q] - mx);   // masked -> exp(-1e4 - mx) == 0
        sloc += e;
        vloc += e * mk[q] * hbq[q];
    }
    #pragma unroll
    for (int off = 32; off >= 1; off >>= 1) {
        sloc += __shfl_xor(sloc, off);
        vloc += __shfl_xor(vloc, off);
    }
    if ((tid & 63) == 0) { red[4 + (tid >> 6)] = sloc; red[8 + (tid >> 6)] = vloc; }
    __syncthreads();
    if (tid == 0) {
        const float denom = red[4] + red[5] + red[6] + red[7];
        const float vsum  = red[8] + red[9] + red[10] + red[11];
        out[i] = hdot[i] + vsum / denom + fc_b[0];
    }
}

// ---------------------------------------------------------------------------
extern "C" void kernel_launch(void* const* d_in, const int* in_sizes, int n_in,
                              void* d_out, int out_size, void* d_ws, size_t ws_size,
                              hipStream_t stream)
{
    const float* x     = (const float*)d_in[0];
    const float* rel   = (const float*)d_in[1];
    const float* W     = (const float*)d_in[2];
    const float* b     = (const float*)d_in[3];
    const float* fc_w  = (const float*)d_in[4];
    const float* fc_b  = (const float*)d_in[5];
    const float* Wih0  = (const float*)d_in[6];
    const float* Whh0  = (const float*)d_in[7];
    const float* bih0  = (const float*)d_in[8];
    const float* bhh0  = (const float*)d_in[9];
    const float* Wih1  = (const float*)d_in[10];
    const float* Whh1  = (const float*)d_in[11];
    const float* bih1  = (const float*)d_in[12];
    const float* bhh1  = (const float*)d_in[13];

    float* ws   = (float*)d_ws;
    float* sa   = ws;                         // 1024
    float* sb   = sa   + NN;                  // 1024
    float* hdot = sb   + NN;                  // 1024
    float* hb   = hdot + NN;                  // 1024
    float* sr   = hb   + NN;                  // 1024*1024
    float* ssum = sr   + (size_t)NN * NN;     // 1024*1024

    k_rel<<<1024, 256, 0, stream>>>(rel, W, sr, ssum);
    k_gru<<<NN / SS, 192, 0, stream>>>(x, W, fc_w,
                                       Wih0, Whh0, bih0, bhh0,
                                       Wih1, Whh1, bih1, bhh1,
                                       sa, sb, hdot, hb);
    k2<<<NN, 256, 0, stream>>>(sa, sb, hdot, hb, sr, ssum,
                               b, fc_b, (float*)d_out);
}